// Round 1
// baseline (486.926 us; speedup 1.0000x reference)
//
#include <hip/hip_runtime.h>

#define BS 16
#define CI 2048
#define NI 16
#define CO 64
#define NO 32
#define KK 2048  // CO*NO

// MODE 0: iter1 (uniform route) -> accumulate raw vote sums
// MODE 1: iter2 (logits = dist, write logits)
// MODE 2: iter3 (logits = stored + dist, no write)
template <int MODE>
__global__ __launch_bounds__(1024) void pass_kernel(
    const float* __restrict__ x,      // [BS][CI][NI]
    const float* __restrict__ w,      // [CI][NI][KK]
    const float* __restrict__ act_in, // [BS][KK] (null for MODE 0)
    float* __restrict__ logits,       // [BS][CI][CO]
    float* __restrict__ partials,     // [G][BS][KK]
    int G)
{
    __shared__ float x_lds[BS * NI];
    __shared__ float sm[1024];

    const int t = threadIdx.x;        // 0..1023
    const int blk = blockIdx.x;
    const int k0 = 2 * t;             // this thread's pair of k
    const int co = t >> 4;            // k0/32

    float2 acc[BS];
#pragma unroll
    for (int b = 0; b < BS; ++b) acc[b] = make_float2(0.f, 0.f);

    for (int i = blk; i < CI; i += G) {
        // stage x[:, i, :] (256 floats)
        if (t < BS * NI) {
            int b = t >> 4, ni = t & 15;
            x_lds[t] = x[((size_t)b * CI + i) * NI + ni];
        }
        __syncthreads();

        const float* wrow = w + ((size_t)i * NI) * KK + k0;

        auto votes_into = [&](float2(&vv)[BS]) {
#pragma unroll
            for (int nig = 0; nig < 4; ++nig) {
                float2 wr0 = *(const float2*)(wrow + (size_t)(nig * 4 + 0) * KK);
                float2 wr1 = *(const float2*)(wrow + (size_t)(nig * 4 + 1) * KK);
                float2 wr2 = *(const float2*)(wrow + (size_t)(nig * 4 + 2) * KK);
                float2 wr3 = *(const float2*)(wrow + (size_t)(nig * 4 + 3) * KK);
#pragma unroll
                for (int b = 0; b < BS; ++b) {
                    float4 xv = *(const float4*)&x_lds[b * NI + nig * 4];
                    vv[b].x = fmaf(xv.x, wr0.x, vv[b].x);
                    vv[b].y = fmaf(xv.x, wr0.y, vv[b].y);
                    vv[b].x = fmaf(xv.y, wr1.x, vv[b].x);
                    vv[b].y = fmaf(xv.y, wr1.y, vv[b].y);
                    vv[b].x = fmaf(xv.z, wr2.x, vv[b].x);
                    vv[b].y = fmaf(xv.z, wr2.y, vv[b].y);
                    vv[b].x = fmaf(xv.w, wr3.x, vv[b].x);
                    vv[b].y = fmaf(xv.w, wr3.y, vv[b].y);
                }
            }
        };

        if constexpr (MODE == 0) {
            // uniform route: accumulate votes directly
            votes_into(acc);
            __syncthreads();  // protect x_lds for next stage
        } else {
            float2 v[BS];
#pragma unroll
            for (int b = 0; b < BS; ++b) v[b] = make_float2(0.f, 0.f);
            votes_into(v);

            // distances: dp[b] = sum_no votes[b,co,no]*act[b,co,no]
            float dp[BS];
#pragma unroll
            for (int b = 0; b < BS; ++b) {
                float2 a = *(const float2*)&act_in[(size_t)b * KK + k0];
                dp[b] = v[b].x * a.x + v[b].y * a.y;
            }
            // reduce over the 16-lane group sharing this co
#pragma unroll
            for (int b = 0; b < BS; ++b) {
#pragma unroll
                for (int m = 1; m < 16; m <<= 1)
                    dp[b] += __shfl_xor(dp[b], m, 16);
            }
            // each lane in the group owns one b
            sm[(t & 15) * CO + co] = dp[t & 15];
            __syncthreads();

            // softmax: thread t handles (b = t>>6, co = t&63); sm[t] == dist[b][co]
            float d = sm[t];
            float lg;
            size_t lidx = ((size_t)(t >> 6) * CI + i) * CO + (t & 63);
            if constexpr (MODE == 1) {
                lg = d;
                logits[lidx] = lg;
            } else {
                lg = logits[lidx] + d;
            }
            float mx = lg;
#pragma unroll
            for (int m = 1; m < 64; m <<= 1) mx = fmaxf(mx, __shfl_xor(mx, m, 64));
            float e = __expf(lg - mx);
            float s = e;
#pragma unroll
            for (int m = 1; m < 64; m <<= 1) s += __shfl_xor(s, m, 64);
            float route = e / s;
            sm[t] = route;   // same slot this thread read; no cross-thread hazard
            __syncthreads();

            // accumulate routed votes
#pragma unroll
            for (int b = 0; b < BS; ++b) {
                float r = sm[b * CO + co];
                acc[b].x = fmaf(r, v[b].x, acc[b].x);
                acc[b].y = fmaf(r, v[b].y, acc[b].y);
            }
            __syncthreads();  // protect sm and x_lds before next i
        }
    }

    // write per-block partial preactivations
#pragma unroll
    for (int b = 0; b < BS; ++b) {
        *(float2*)&partials[((size_t)blk * BS + b) * KK + k0] = acc[b];
    }
}

__global__ __launch_bounds__(256) void reduce_squash(
    const float* __restrict__ partials, int G,
    const float* __restrict__ bias,
    float* __restrict__ act_out, float scale)
{
    int tid = blockIdx.x * 256 + threadIdx.x;  // 0..32767
    int b = tid >> 11;    // /KK
    int k = tid & (KK - 1);
    float s = 0.f;
    for (int g = 0; g < G; ++g)
        s += partials[((size_t)g * BS + b) * KK + k];
    float v = s * scale + bias[k];
    // squash over the 32-no group (consecutive lanes, 32-aligned)
    float n2 = v * v;
#pragma unroll
    for (int m = 1; m < 32; m <<= 1) n2 += __shfl_xor(n2, m, 32);
    float norm = sqrtf(n2);
    act_out[tid] = v * norm / (1.f + n2);
}

extern "C" void kernel_launch(void* const* d_in, const int* in_sizes, int n_in,
                              void* d_out, int out_size, void* d_ws, size_t ws_size,
                              hipStream_t stream) {
    const float* x = (const float*)d_in[0];
    const float* w = (const float*)d_in[1];
    const float* bias = (const float*)d_in[2];
    float* out = (float*)d_out;

    // workspace layout: partials[G][BS][KK] | logits[BS][CI][CO] | act1 | act2
    const size_t fixed = (size_t)BS * CI * CO * 4 + 2 * (size_t)BS * KK * 4;
    int G = 256;
    while (G > 8 && fixed + (size_t)G * BS * KK * 4 > ws_size) G >>= 1;

    char* p = (char*)d_ws;
    float* partials = (float*)p; p += (size_t)G * BS * KK * 4;
    float* logits = (float*)p;   p += (size_t)BS * CI * CO * 4;
    float* act1 = (float*)p;     p += (size_t)BS * KK * 4;
    float* act2 = (float*)p;

    dim3 blk(1024), grid(G);
    // iteration 1 (uniform route)
    pass_kernel<0><<<grid, blk, 0, stream>>>(x, w, nullptr, logits, partials, G);
    reduce_squash<<<128, 256, 0, stream>>>(partials, G, bias, act1, 1.0f / (float)CO);
    // iteration 2
    pass_kernel<1><<<grid, blk, 0, stream>>>(x, w, act1, logits, partials, G);
    reduce_squash<<<128, 256, 0, stream>>>(partials, G, bias, act2, 1.0f);
    // iteration 3 (final; logit update after is dead in the reference)
    pass_kernel<2><<<grid, blk, 0, stream>>>(x, w, act2, logits, partials, G);
    reduce_squash<<<128, 256, 0, stream>>>(partials, G, bias, out, 1.0f);
}